// Round 10
// baseline (140.612 us; speedup 1.0000x reference)
//
#include <hip/hip_runtime.h>
#include <hip/hip_bf16.h>

// ScaledDotProductAttentionEnriched: BH=64, S=1024, DK=64, FG=FL=32.
// R14 = R12 (verified best: 43.0us main, fragment-major image, R0 schedule)
// + two changes, sleep reverted (R13 null):
//  (1) mask-bias fragment EXCISED: the dc=8 b128 read + 32x32x16 MFMA per
//      wave-tile only made exp2 underflow to 0 for masked k. Prep now emits
//      a 64-bit ballot per (bh,tile); main does p = masked ? 0 : exp2(s)
//      (one cndmask/elem; bit via compile-time shifts of the per-lane
//      pre-shifted ballot word, k_row(r,h)=(r&3)+8(r>>2)+4h). Numerically
//      identical. Saves 1/9 of LDS reads + MFMAs + DMA; tile 26.6->24KB
//      = exactly 24 chunks -> branch-free 3 DMA chunks/wave.
//  (2) V ds_reads issued BEFORE the QK MFMA cluster (PV's LDS-pipe work
//      overlaps QK's MFMA issue; +16 VGPR).
// Schedule (barrier + end-of-iter vmcnt(0), double-buffer, 512thr 4qh x 2kp,
// setprio) unchanged from R12.

#define BHn 64
#define Sn  1024
#define NT  16
#define TILESZ 24576          // 16KB K-frags (2kp x 8dc x 2h x 512) + 8KB V
#define KIMG2  16384
#define OSTR 68
// s_waitcnt imm: vmcnt=0, expcnt=7 (no wait), lgkmcnt=15 (no wait)
#define WAIT_VM0 0x0F70

typedef __attribute__((ext_vector_type(8)))  __bf16 bf16x8;
typedef __attribute__((ext_vector_type(16))) float  f32x16;
typedef __attribute__((ext_vector_type(4)))  unsigned int u32x4;

__device__ __forceinline__ unsigned f2bf1(float a){
    union { float f; unsigned u; } c; c.f = a;
    return (c.u + 0x7fffu + ((c.u >> 16) & 1u)) >> 16;   // RNE f32->bf16
}
__device__ __forceinline__ unsigned f2bf2(float a, float b){
    return f2bf1(a) | (f2bf1(b) << 16);
}
// (bf16_trunc(b)<<16)|bf16_trunc(a) in one v_perm_b32
__device__ __forceinline__ unsigned pkbf(float a, float b){
    return __builtin_amdgcn_perm(__builtin_bit_cast(unsigned, b),
                                 __builtin_bit_cast(unsigned, a), 0x07060302u);
}
__device__ __forceinline__ void gld_lds16(const void* g, void* l){
    __builtin_amdgcn_global_load_lds(
        (const __attribute__((address_space(1))) unsigned int*)g,
        (__attribute__((address_space(3))) unsigned int*)l, 16, 0, 0);
}

// ---------------- prep: fp32 -> bf16 fragment-major image via LDS bounce ----
// K-frag slot (kp,dc,h):  ((kp*8+dc)*2+h)*512 + l31*16   (rows kp*32+l31,
//   cols dc*16+8h..+8, bf16x8 = 16B/lane) -> wave reads kp*8192 + dc*1024
//   + lane*16 as one contiguous 1KB block (h = lane>>5).
// V-frag slot (kp,dt,j,h): KIMG2 + (((kp*2+dt)*2+j)*2+h)*512 + l31*16
//   (tau-permuted V^T rows dt*32+l31, k-cols kp*32+j*16+8h..+8).
// Mask: 64-bit ballot of (M==1) per (bh,tile) -> Mb[bh*NT+ti].
__global__ __launch_bounds__(256)
void attn_prep(const float* __restrict__ K, const float* __restrict__ V,
               const float* __restrict__ LF, const float* __restrict__ GF,
               const int* __restrict__ M, unsigned short* __restrict__ P,
               unsigned long long* __restrict__ Mb)
{
    __shared__ __align__(16) unsigned char plds[TILESZ];   // exact tile image

    const int tid = threadIdx.x;
    const int bh = blockIdx.x >> 4, ti = blockIdx.x & 15, kb = ti*64;

    // K cols 0..63: 64 rows x 8 col-groups of 8 -> slots (kp, dc=c>>1, h=c&1)
    #pragma unroll
    for (int i=0;i<2;i++){
        int idx = tid + 256*i, row = idx>>3, c = idx&7;
        const float* s = K + ((size_t)bh*Sn + kb + row)*64 + c*8;
        float4 f0 = *(const float4*)s, f1 = *(const float4*)(s+4);
        u32x4 w; w[0]=f2bf2(f0.x,f0.y); w[1]=f2bf2(f0.z,f0.w);
        w[2]=f2bf2(f1.x,f1.y); w[3]=f2bf2(f1.z,f1.w);
        int kp = row>>5, l31 = row&31, dc = c>>1, h = c&1;
        *(u32x4*)(plds + ((kp*8+dc)*2+h)*512 + l31*16) = w;
    }
    // GF cols 64..95 -> dc = 4+(c2>>1), h = c2&1
    {
        int row = tid>>2, c2 = tid&3;
        const float* s = GF + ((size_t)bh*Sn + kb + row)*32 + c2*8;
        float4 f0 = *(const float4*)s, f1 = *(const float4*)(s+4);
        u32x4 w; w[0]=f2bf2(f0.x,f0.y); w[1]=f2bf2(f0.z,f0.w);
        w[2]=f2bf2(f1.x,f1.y); w[3]=f2bf2(f1.z,f1.w);
        int kp = row>>5, l31 = row&31, dc = 4+(c2>>1), h = c2&1;
        *(u32x4*)(plds + ((kp*8+dc)*2+h)*512 + l31*16) = w;
    }
    // LF cols 96..127 -> dc = 6+(c2>>1), h = c2&1
    {
        int row = tid>>2, c2 = tid&3;
        const float* s = LF + ((size_t)bh*Sn + kb + row)*32 + c2*8;
        float4 f0 = *(const float4*)s, f1 = *(const float4*)(s+4);
        u32x4 w; w[0]=f2bf2(f0.x,f0.y); w[1]=f2bf2(f0.z,f0.w);
        w[2]=f2bf2(f1.x,f1.y); w[3]=f2bf2(f1.z,f1.w);
        int kp = row>>5, l31 = row&31, dc = 6+(c2>>1), h = c2&1;
        *(u32x4*)(plds + ((kp*8+dc)*2+h)*512 + l31*16) = w;
    }
    // mask ballot: wave 0 (tid 0..63) covers this tile's 64 k-rows
    if (tid < 64){
        int mv = M[(size_t)bh*Sn + kb + tid];
        unsigned long long bal = __ballot(mv == 1);
        if (tid == 0) Mb[bh*NT + ti] = bal;
    }
    // tau-permuted V^T (quads 1<->2 within each 16)
    {
        int d = tid & 63, g = tid >> 6;                // g: k-octet 0..3
        const float* vb = V + ((size_t)bh*Sn + kb + 16*g)*64 + d;
        const int pm[16] = {0,1,2,3, 8,9,10,11, 4,5,6,7, 12,13,14,15};
        unsigned w[8];
        #pragma unroll
        for (int m=0;m<8;m++)
            w[m] = f2bf2(vb[(size_t)pm[2*m]*64], vb[(size_t)pm[2*m+1]*64]);
        u32x4 a, b;
        a[0]=w[0]; a[1]=w[1]; a[2]=w[2]; a[3]=w[3];    // h=0 half
        b[0]=w[4]; b[1]=w[5]; b[2]=w[6]; b[3]=w[7];    // h=1 half
        int kp = g>>1, j = g&1, dt = d>>5, l31 = d&31;
        unsigned char* vs = plds + KIMG2 + (((kp*2+dt)*2+j)*2)*512 + l31*16;
        *(u32x4*)(vs)       = a;
        *(u32x4*)(vs + 512) = b;
    }
    __syncthreads();

    // flat, full-line coalesced dump LDS -> global image (24KB = 6 x 4096)
    unsigned char* dP = (unsigned char*)P + (size_t)(bh*NT + ti)*TILESZ;
    #pragma unroll
    for (int i=0;i<6;i++){
        int off = tid*16 + i*4096;
        *(u32x4*)(dP + off) = *(const u32x4*)(plds + off);
    }
}

// ---------------- main: R12 schedule, bias-free QK, 512 threads ------------
__global__ __launch_bounds__(512, 4)
void attn_main(const float* __restrict__ Q, const unsigned short* __restrict__ P,
               const unsigned long long* __restrict__ Mb,
               const float* __restrict__ GF, const float* __restrict__ LF,
               float* __restrict__ O)
{
    __shared__ __align__(16) unsigned char smem[2*TILESZ];   // 49152 B
    const int tid  = threadIdx.x;
    const int wave = tid >> 6, lane = tid & 63;
    const int l31  = lane & 31, h = lane >> 5;
    const int qh   = wave >> 1;   // q-subtile 0..3
    const int kp   = wave & 1;    // k-half
    const int bh = blockIdx.x & 63;   // same-bh blocks 64 apart -> same XCD
    const int qb = blockIdx.x >> 6;   // 0..7
    const float SCL = 0.18033688011112042f;  // 0.125 * log2(e)

    // Q fragments, B-layout B[d=16*dc+8h+j][q=l31]
    const int qrow = qb*128 + qh*32 + l31;
    u32x4 qf[8];
    #pragma unroll
    for (int dc = 0; dc < 8; dc++){
        const int cb = dc*16 + 8*h;
        const float* src;
        if (cb < 64)      src = Q  + ((size_t)bh*Sn + qrow)*64 + cb;
        else if (cb < 96) src = GF + ((size_t)bh*Sn + qrow)*32 + (cb - 64);
        else              src = LF + ((size_t)bh*Sn + qrow)*32 + (cb - 96);
        float4 f0 = *(const float4*)src;
        float4 f1 = *(const float4*)(src + 4);
        qf[dc][0] = f2bf2(f0.x*SCL, f0.y*SCL);
        qf[dc][1] = f2bf2(f0.z*SCL, f0.w*SCL);
        qf[dc][2] = f2bf2(f1.x*SCL, f1.y*SCL);
        qf[dc][3] = f2bf2(f1.z*SCL, f1.w*SCL);
    }

    f32x16 oacc[2];
    #pragma unroll
    for (int dt=0; dt<2; dt++)
        #pragma unroll
        for (int r=0; r<16; r++) oacc[dt][r] = 0.f;
    float lrun = 0.f;

    const unsigned char* gTb = (const unsigned char*)P + (size_t)bh*NT*TILESZ;

    // prologue: stage tile 0 into buffer 0 (24 chunks, 3/wave), drain
    #pragma unroll
    for (int i=0;i<3;i++){
        int c = wave + 8*i;
        gld_lds16(gTb + (size_t)c*1024 + lane*16, smem + c*1024);
    }
    __builtin_amdgcn_s_waitcnt(WAIT_VM0);   // my tile-0 DMA has landed

    for (int t = 0; t < NT; t++){
        unsigned char* cur = smem + (size_t)(t&1)*TILESZ;
        unsigned char* nxt = smem + (size_t)((t+1)&1)*TILESZ;
        // every wave arrives with vmcnt==0 -> after barrier tile t is in LDS
        __syncthreads();
        if (t+1 < NT){
            const unsigned char* gT = gTb + (size_t)(t+1)*TILESZ;
            #pragma unroll
            for (int i=0;i<3;i++){
                int c = wave + 8*i;
                gld_lds16(gT + (size_t)c*1024 + lane*16, nxt + c*1024);
            }
        }
        const unsigned char* kt = cur + kp*8192 + lane*16;
        const unsigned char* vt = cur + KIMG2 + kp*4096 + lane*16;

        // V fragments issued EARLY: their LDS-pipe time overlaps QK's MFMAs
        u32x4 va00 = *(const u32x4*)(vt);
        u32x4 va01 = *(const u32x4*)(vt + 1024);
        u32x4 va10 = *(const u32x4*)(vt + 2048);
        u32x4 va11 = *(const u32x4*)(vt + 3072);

        // S^T(32k x 32q): 8 fragment-major b128 reads feed 8 MFMAs
        f32x16 acc;
        #pragma unroll
        for (int r=0;r<16;r++) acc[r] = 0.f;
        __builtin_amdgcn_s_setprio(1);
        #pragma unroll
        for (int dc=0; dc<8; dc++){
            u32x4 ar = *(const u32x4*)(kt + dc*1024);
            acc = __builtin_amdgcn_mfma_f32_32x32x16_bf16(
                    __builtin_bit_cast(bf16x8, ar),
                    __builtin_bit_cast(bf16x8, qf[dc]), acc, 0, 0, 0);
        }
        __builtin_amdgcn_s_setprio(0);

        // mask word for this tile: per-lane pre-shift by 4h, then the bit for
        // acc[r] is at compile-time position (r&3)+8*(r>>2)
        unsigned long long mw = Mb[bh*NT + t];
        unsigned w32 = kp ? (unsigned)(mw >> 32) : (unsigned)mw;
        unsigned wsh = w32 >> (4*h);

        // no-max softmax with exact-zero masking: p = masked ? 0 : exp2(s)
        float p[16];
        #pragma unroll
        for (int r=0;r<16;r++){
            float pr = __builtin_amdgcn_exp2f(acc[r]);
            unsigned bit = (wsh >> ((r&3)+8*(r>>2))) & 1u;
            p[r] = bit ? 0.f : pr;
        }
        // tree-sum the denominator (depth 4)
        float s4[8];
        #pragma unroll
        for (int r=0;r<8;r++) s4[r] = p[2*r] + p[2*r+1];
        #pragma unroll
        for (int r=0;r<4;r++) s4[r] = s4[2*r] + s4[2*r+1];
        lrun += (s4[0]+s4[1]) + (s4[2]+s4[3]);

        // P C-layout -> B-operand directly (tau baked into the V image)
        unsigned pk[8];
        #pragma unroll
        for (int i=0;i<8;i++) pk[i] = pkbf(p[2*i], p[2*i+1]);
        u32x4 b0, b1;
        b0[0]=pk[0]; b0[1]=pk[1]; b0[2]=pk[2]; b0[3]=pk[3];
        b1[0]=pk[4]; b1[1]=pk[5]; b1[2]=pk[6]; b1[3]=pk[7];

        // O^T += V^T * P over this wave's 32 k
        __builtin_amdgcn_s_setprio(1);
        oacc[0] = __builtin_amdgcn_mfma_f32_32x32x16_bf16(
                __builtin_bit_cast(bf16x8, va00),
                __builtin_bit_cast(bf16x8, b0), oacc[0], 0, 0, 0);
        oacc[0] = __builtin_amdgcn_mfma_f32_32x32x16_bf16(
                __builtin_bit_cast(bf16x8, va01),
                __builtin_bit_cast(bf16x8, b1), oacc[0], 0, 0, 0);
        oacc[1] = __builtin_amdgcn_mfma_f32_32x32x16_bf16(
                __builtin_bit_cast(bf16x8, va10),
                __builtin_bit_cast(bf16x8, b0), oacc[1], 0, 0, 0);
        oacc[1] = __builtin_amdgcn_mfma_f32_32x32x16_bf16(
                __builtin_bit_cast(bf16x8, va11),
                __builtin_bit_cast(bf16x8, b1), oacc[1], 0, 0, 0);
        __builtin_amdgcn_s_setprio(0);

        // drain my prefetch (t+1) AFTER compute-t hid its latency
        __builtin_amdgcn_s_waitcnt(WAIT_VM0);
    }

    // epilogue: combine k-halves via LDS, normalize, coalesced stores
    __syncthreads();
    float lw = lrun + __shfl_xor(lrun, 32, 64);   // per-q sum, this k-half
    float* s1 = (float*)smem;                     // [128 q][OSTR]
    float* s2 = (float*)(smem + 128*OSTR*4);      // [128] l partials
    if (kp == 1){
        #pragma unroll
        for (int dt=0;dt<2;dt++)
            #pragma unroll
            for (int rg=0;rg<4;rg++){
                float4 w;
                w.x = oacc[dt][rg*4+0]; w.y = oacc[dt][rg*4+1];
                w.z = oacc[dt][rg*4+2]; w.w = oacc[dt][rg*4+3];
                *(float4*)(s1 + (qh*32 + l31)*OSTR + dt*32 + rg*8 + 4*h) = w;
            }
        if (h == 0) s2[qh*32 + l31] = lw;
    }
    __syncthreads();
    if (kp == 0){
        float inv = 1.0f / (lw + s2[qh*32 + l31]);
        #pragma unroll
        for (int dt=0;dt<2;dt++)
            #pragma unroll
            for (int rg=0;rg<4;rg++){
                float* p = s1 + (qh*32 + l31)*OSTR + dt*32 + rg*8 + 4*h;
                float4 w = *(float4*)p;
                w.x = (w.x + oacc[dt][rg*4+0])*inv;
                w.y = (w.y + oacc[dt][rg*4+1])*inv;
                w.z = (w.z + oacc[dt][rg*4+2])*inv;
                w.w = (w.w + oacc[dt][rg*4+3])*inv;
                *(float4*)p = w;
            }
    }
    __syncthreads();
    #pragma unroll
    for (int i=0;i<4;i++){
        int idx = tid + 512*i, r = idx>>4, c = idx&15;
        *(float4*)(O + ((size_t)bh*Sn + qb*128 + r)*64 + c*4) =
            *(const float4*)(s1 + r*OSTR + c*4);
    }
}

extern "C" void kernel_launch(void* const* d_in, const int* in_sizes, int n_in,
                              void* d_out, int out_size, void* d_ws, size_t ws_size,
                              hipStream_t stream) {
    const float* Q  = (const float*)d_in[0];
    const float* K  = (const float*)d_in[1];
    const float* V  = (const float*)d_in[2];
    const float* LF = (const float*)d_in[3];
    const float* GF = (const float*)d_in[4];
    const int*   M  = (const int*)d_in[5];
    float* O = (float*)d_out;

    unsigned short*     P  = (unsigned short*)d_ws;      // 25,165,824 B
    unsigned long long* Mb = (unsigned long long*)((char*)d_ws + (size_t)BHn*NT*TILESZ);

    attn_prep<<<dim3(BHn*NT), dim3(256), 0, stream>>>(K, V, LF, GF, M, P, Mb);
    attn_main<<<dim3(BHn*(Sn/128)), dim3(512), 0, stream>>>(Q, P, Mb, GF, LF, O);
}